// Round 1
// baseline (134.052 us; speedup 1.0000x reference)
//
#include <hip/hip_runtime.h>
#include <math.h>

#define EPSF 1e-9f

// One element per loop iteration: coalesced float4 box loads (16 B/lane),
// fp32 CIoU, masked iou written to out[1+i], masked loss term accumulated
// thread -> wave (shfl, width 64) -> block (LDS) -> one atomicAdd per block.
__global__ __launch_bounds__(256) void box_loss_kernel(
    const float4* __restrict__ pb, const float4* __restrict__ tb,
    const int*    __restrict__ mask, const float* __restrict__ bnorm,
    const float*  __restrict__ cls_norm, float* __restrict__ out, int n)
{
    const int stride = gridDim.x * blockDim.x;
    float acc = 0.0f;
    for (int i = blockIdx.x * blockDim.x + threadIdx.x; i < n; i += stride) {
        const float4 a = pb[i];
        const float4 b = tb[i];

        float iw = fminf(a.z, b.z) - fmaxf(a.x, b.x); iw = fmaxf(iw, 0.0f);
        float ih = fminf(a.w, b.w) - fmaxf(a.y, b.y); ih = fmaxf(ih, 0.0f);
        float inter = iw * ih;

        float wa = a.z - a.x, ha = a.w - a.y;
        float wb = b.z - b.x, hb = b.w - b.y;
        float uni = wa * ha + wb * hb - inter;
        float iou = inter / (uni + EPSF);

        float cw = fmaxf(a.z, b.z) - fminf(a.x, b.x);
        float ch = fmaxf(a.w, b.w) - fminf(a.y, b.y);
        float c2 = cw * cw + ch * ch + EPSF;

        float dx = (b.x + b.z - a.x - a.z) * 0.5f;
        float dy = (b.y + b.w - a.y - a.w) * 0.5f;
        float rho2 = dx * dx + dy * dy;

        float datan = atanf(wb / (hb + EPSF)) - atanf(wa / (ha + EPSF));
        const float c4pi2 = 4.0f / (float)(M_PI * M_PI);
        float v = c4pi2 * datan * datan;
        float alpha = v / (1.0f - iou + v + EPSF);

        float ciou = iou - rho2 / c2 - alpha * v;

        float m = (float)mask[i];          // jax bool -> int32 per harness
        float iou_m = ciou * m;
        out[1 + i] = iou_m;
        acc += (1.0f - iou_m) * bnorm[i] * m;
    }

    // wave64 butterfly reduction
    #pragma unroll
    for (int off = 32; off > 0; off >>= 1)
        acc += __shfl_down(acc, off, 64);

    __shared__ float lds[4];
    const int lane = threadIdx.x & 63;
    const int wid  = threadIdx.x >> 6;
    if (lane == 0) lds[wid] = acc;
    __syncthreads();
    if (threadIdx.x == 0) {
        float s = lds[0] + lds[1] + lds[2] + lds[3];
        atomicAdd(out, s / cls_norm[0]);   // device-scope by default
    }
}

extern "C" void kernel_launch(void* const* d_in, const int* in_sizes, int n_in,
                              void* d_out, int out_size, void* d_ws, size_t ws_size,
                              hipStream_t stream) {
    const float4* pb    = (const float4*)d_in[0];  // predicts_bbox [B,A,4]
    const float4* tb    = (const float4*)d_in[1];  // targets_bbox  [B,A,4]
    const int*    mask  = (const int*)  d_in[2];   // valid_masks   [B,A]
    const float*  bnorm = (const float*)d_in[3];   // box_norm      [B,A]
    const float*  cls   = (const float*)d_in[4];   // cls_norm scalar
    float*        out   = (float*)d_out;           // [loss_iou, iou...]
    const int n = in_sizes[2];                     // B*A = 2,150,400

    // d_out is poisoned 0xAA before every timed launch -> zero the accumulator.
    hipMemsetAsync(d_out, 0, sizeof(float), stream);

    const int block = 256;
    const int grid  = 2048;  // grid-stride, ~4 elems/thread, 2048 atomics total
    box_loss_kernel<<<grid, block, 0, stream>>>(pb, tb, mask, bnorm, cls, out, n);
}

// Round 2
// 133.988 us; speedup vs baseline: 1.0005x; 1.0005x over previous
//
#include <hip/hip_runtime.h>
#include <math.h>

#define EPSF 1e-9f
#define UNROLL 4

// Cheap atan: degree-9 odd minimax poly on [0,1], range-reduce via
// atan(z) = pi/2 - atan(1/z) for |z|>1. Max abs err ~1e-5 (threshold 2.6e-2).
__device__ __forceinline__ float fast_atan(float z) {
    float az = fabsf(z);
    float rz = __builtin_amdgcn_rcpf(az);
    float t  = az > 1.0f ? rz : az;          // t in [0,1]
    float t2 = t * t;
    float p = fmaf(t2, 0.0208351f, -0.0851330f);
    p = fmaf(t2, p, 0.1801410f);
    p = fmaf(t2, p, -0.3302995f);
    p = fmaf(t2, p, 0.9998660f);
    p = p * t;
    float r = az > 1.0f ? 1.5707963f - p : p;
    return z < 0.0f ? -r : r;
}

__device__ __forceinline__ float ciou_masked(float4 a, float4 b, float m,
                                             float bn, float* acc) {
    float iw = fminf(a.z, b.z) - fmaxf(a.x, b.x); iw = fmaxf(iw, 0.0f);
    float ih = fminf(a.w, b.w) - fmaxf(a.y, b.y); ih = fmaxf(ih, 0.0f);
    float inter = iw * ih;

    float wa = a.z - a.x, ha = a.w - a.y;
    float wb = b.z - b.x, hb = b.w - b.y;
    float uni = wa * ha + wb * hb - inter;
    float iou = inter * __builtin_amdgcn_rcpf(uni + EPSF);

    float cw = fmaxf(a.z, b.z) - fminf(a.x, b.x);
    float ch = fmaxf(a.w, b.w) - fminf(a.y, b.y);
    float c2 = fmaf(cw, cw, fmaf(ch, ch, EPSF));

    float dx = (b.x + b.z - a.x - a.z) * 0.5f;
    float dy = (b.y + b.w - a.y - a.w) * 0.5f;
    float rho2 = fmaf(dx, dx, dy * dy);

    // atan(wb/hb') - atan(wa/ha') = atan((wb*ha' - wa*hb')/(ha'*hb' + wa*wb))
    float hap = ha + EPSF, hbp = hb + EPSF;
    float num = fmaf(wb, hap, -wa * hbp);
    float den = fmaf(hap, hbp, wa * wb);
    float datan = fast_atan(num * __builtin_amdgcn_rcpf(den));

    const float c4pi2 = 0.40528473456f;      // 4/pi^2
    float v = c4pi2 * datan * datan;
    float av = v * v * __builtin_amdgcn_rcpf(1.0f - iou + v + EPSF); // alpha*v

    float ciou = iou - rho2 * __builtin_amdgcn_rcpf(c2) - av;
    float iou_m = ciou * m;
    *acc += (1.0f - iou_m) * bn * m;
    return iou_m;
}

__global__ __launch_bounds__(256) void box_loss_kernel(
    const float4* __restrict__ pb, const float4* __restrict__ tb,
    const int*    __restrict__ mask, const float* __restrict__ bnorm,
    const float*  __restrict__ cls_norm, float* __restrict__ out, int n)
{
    const int stride = gridDim.x * blockDim.x;      // one UNROLL-chunk pass
    const int tid = blockIdx.x * blockDim.x + threadIdx.x;
    float acc = 0.0f;

    // All loads for UNROLL elements issued before any compute -> 4x MLP.
    float4 a[UNROLL], b[UNROLL];
    int    mk[UNROLL];
    float  bn[UNROLL];
    int    idx[UNROLL];
    #pragma unroll
    for (int u = 0; u < UNROLL; ++u) {
        int i = tid + u * stride;
        idx[u] = i;
        if (i < n) { a[u] = pb[i]; b[u] = tb[i]; mk[u] = mask[i]; bn[u] = bnorm[i]; }
        else       { mk[u] = 0; bn[u] = 0.0f;
                     a[u] = make_float4(0,0,1,1); b[u] = make_float4(0,0,1,1); }
    }
    #pragma unroll
    for (int u = 0; u < UNROLL; ++u) {
        float r = ciou_masked(a[u], b[u], (float)mk[u], bn[u], &acc);
        if (idx[u] < n) out[1 + idx[u]] = r;
    }

    // wave64 reduction
    #pragma unroll
    for (int off = 32; off > 0; off >>= 1)
        acc += __shfl_down(acc, off, 64);

    __shared__ float lds[4];
    const int lane = threadIdx.x & 63;
    const int wid  = threadIdx.x >> 6;
    if (lane == 0) lds[wid] = acc;
    __syncthreads();
    if (threadIdx.x == 0) {
        float s = lds[0] + lds[1] + lds[2] + lds[3];
        atomicAdd(out, s / cls_norm[0]);
    }
}

extern "C" void kernel_launch(void* const* d_in, const int* in_sizes, int n_in,
                              void* d_out, int out_size, void* d_ws, size_t ws_size,
                              hipStream_t stream) {
    const float4* pb    = (const float4*)d_in[0];
    const float4* tb    = (const float4*)d_in[1];
    const int*    mask  = (const int*)  d_in[2];
    const float*  bnorm = (const float*)d_in[3];
    const float*  cls   = (const float*)d_in[4];
    float*        out   = (float*)d_out;
    const int n = in_sizes[2];                    // B*A = 2,150,400

    hipMemsetAsync(d_out, 0, sizeof(float), stream);

    const int block = 256;
    const int per_block = block * UNROLL;         // 1024 elems/block
    const int grid = (n + per_block - 1) / per_block;  // 2100 for n=2150400
    box_loss_kernel<<<grid, block, 0, stream>>>(pb, tb, mask, bnorm, cls, out, n);
}

// Round 3
// 123.194 us; speedup vs baseline: 1.0881x; 1.0876x over previous
//
#include <hip/hip_runtime.h>
#include <math.h>

#define EPSF 1e-9f
#define UNROLL 4

// Cheap atan: degree-9 odd minimax poly on [0,1], range-reduce via
// atan(z) = pi/2 - atan(1/z) for |z|>1. Max abs err ~1e-5 (threshold 2.6e-2).
__device__ __forceinline__ float fast_atan(float z) {
    float az = fabsf(z);
    float rz = __builtin_amdgcn_rcpf(az);
    float t  = az > 1.0f ? rz : az;          // t in [0,1]
    float t2 = t * t;
    float p = fmaf(t2, 0.0208351f, -0.0851330f);
    p = fmaf(t2, p, 0.1801410f);
    p = fmaf(t2, p, -0.3302995f);
    p = fmaf(t2, p, 0.9998660f);
    p = p * t;
    float r = az > 1.0f ? 1.5707963f - p : p;
    return z < 0.0f ? -r : r;
}

__device__ __forceinline__ float ciou_masked(float4 a, float4 b, float m,
                                             float bn, float* acc) {
    float iw = fminf(a.z, b.z) - fmaxf(a.x, b.x); iw = fmaxf(iw, 0.0f);
    float ih = fminf(a.w, b.w) - fmaxf(a.y, b.y); ih = fmaxf(ih, 0.0f);
    float inter = iw * ih;

    float wa = a.z - a.x, ha = a.w - a.y;
    float wb = b.z - b.x, hb = b.w - b.y;
    float uni = wa * ha + wb * hb - inter;
    float iou = inter * __builtin_amdgcn_rcpf(uni + EPSF);

    float cw = fmaxf(a.z, b.z) - fminf(a.x, b.x);
    float ch = fmaxf(a.w, b.w) - fminf(a.y, b.y);
    float c2 = fmaf(cw, cw, fmaf(ch, ch, EPSF));

    float dx = (b.x + b.z - a.x - a.z) * 0.5f;
    float dy = (b.y + b.w - a.y - a.w) * 0.5f;
    float rho2 = fmaf(dx, dx, dy * dy);

    // atan(wb/hb') - atan(wa/ha') = atan((wb*ha' - wa*hb')/(ha'*hb' + wa*wb))
    float hap = ha + EPSF, hbp = hb + EPSF;
    float num = fmaf(wb, hap, -wa * hbp);
    float den = fmaf(hap, hbp, wa * wb);
    float datan = fast_atan(num * __builtin_amdgcn_rcpf(den));

    const float c4pi2 = 0.40528473456f;      // 4/pi^2
    float v = c4pi2 * datan * datan;
    float av = v * v * __builtin_amdgcn_rcpf(1.0f - iou + v + EPSF); // alpha*v

    float ciou = iou - rho2 * __builtin_amdgcn_rcpf(c2) - av;
    float iou_m = ciou * m;
    *acc += (1.0f - iou_m) * bn * m;
    return iou_m;
}

// Main kernel: NO global atomics. One partial sum per block -> partials[blockIdx].
__global__ __launch_bounds__(256) void box_loss_main(
    const float4* __restrict__ pb, const float4* __restrict__ tb,
    const int*    __restrict__ mask, const float* __restrict__ bnorm,
    float* __restrict__ iou_out, float* __restrict__ partials, int n)
{
    const int stride = gridDim.x * blockDim.x;
    const int tid = blockIdx.x * blockDim.x + threadIdx.x;
    float acc = 0.0f;

    float4 a[UNROLL], b[UNROLL];
    int    mk[UNROLL];
    float  bn[UNROLL];
    int    idx[UNROLL];
    #pragma unroll
    for (int u = 0; u < UNROLL; ++u) {
        int i = tid + u * stride;
        idx[u] = i;
        if (i < n) { a[u] = pb[i]; b[u] = tb[i]; mk[u] = mask[i]; bn[u] = bnorm[i]; }
        else       { mk[u] = 0; bn[u] = 0.0f;
                     a[u] = make_float4(0,0,1,1); b[u] = make_float4(0,0,1,1); }
    }
    #pragma unroll
    for (int u = 0; u < UNROLL; ++u) {
        float r = ciou_masked(a[u], b[u], (float)mk[u], bn[u], &acc);
        if (idx[u] < n) iou_out[idx[u]] = r;
    }

    // wave64 reduction
    #pragma unroll
    for (int off = 32; off > 0; off >>= 1)
        acc += __shfl_down(acc, off, 64);

    __shared__ float lds[4];
    const int lane = threadIdx.x & 63;
    const int wid  = threadIdx.x >> 6;
    if (lane == 0) lds[wid] = acc;
    __syncthreads();
    if (threadIdx.x == 0)
        partials[blockIdx.x] = lds[0] + lds[1] + lds[2] + lds[3];
}

// Finisher: one block reduces the per-block partials, writes out[0].
__global__ __launch_bounds__(256) void box_loss_final(
    const float* __restrict__ partials, const float* __restrict__ cls_norm,
    float* __restrict__ out, int nblocks)
{
    float acc = 0.0f;
    for (int i = threadIdx.x; i < nblocks; i += 256) acc += partials[i];

    #pragma unroll
    for (int off = 32; off > 0; off >>= 1)
        acc += __shfl_down(acc, off, 64);

    __shared__ float lds[4];
    const int lane = threadIdx.x & 63;
    const int wid  = threadIdx.x >> 6;
    if (lane == 0) lds[wid] = acc;
    __syncthreads();
    if (threadIdx.x == 0)
        out[0] = (lds[0] + lds[1] + lds[2] + lds[3]) / cls_norm[0];
}

extern "C" void kernel_launch(void* const* d_in, const int* in_sizes, int n_in,
                              void* d_out, int out_size, void* d_ws, size_t ws_size,
                              hipStream_t stream) {
    const float4* pb    = (const float4*)d_in[0];
    const float4* tb    = (const float4*)d_in[1];
    const int*    mask  = (const int*)  d_in[2];
    const float*  bnorm = (const float*)d_in[3];
    const float*  cls   = (const float*)d_in[4];
    float*        out   = (float*)d_out;
    float*        part  = (float*)d_ws;           // per-block partials
    const int n = in_sizes[2];                    // B*A = 2,150,400

    const int block = 256;
    const int per_block = block * UNROLL;         // 1024 elems/block
    const int grid = (n + per_block - 1) / per_block;  // 2100

    box_loss_main<<<grid, block, 0, stream>>>(pb, tb, mask, bnorm,
                                              out + 1, part, n);
    box_loss_final<<<1, block, 0, stream>>>(part, cls, out, grid);
}

// Round 4
// 118.136 us; speedup vs baseline: 1.1347x; 1.0428x over previous
//
#include <hip/hip_runtime.h>
#include <math.h>

#define EPSF 1e-9f
#define UNROLL 4

// Cheap atan: degree-9 odd minimax poly on [0,1], range-reduce via
// atan(z) = pi/2 - atan(1/z) for |z|>1. Max abs err ~1e-5 (threshold 2.6e-2).
__device__ __forceinline__ float fast_atan(float z) {
    float az = fabsf(z);
    float rz = __builtin_amdgcn_rcpf(az);
    float t  = az > 1.0f ? rz : az;          // t in [0,1]
    float t2 = t * t;
    float p = fmaf(t2, 0.0208351f, -0.0851330f);
    p = fmaf(t2, p, 0.1801410f);
    p = fmaf(t2, p, -0.3302995f);
    p = fmaf(t2, p, 0.9998660f);
    p = p * t;
    float r = az > 1.0f ? 1.5707963f - p : p;
    return z < 0.0f ? -r : r;
}

__device__ __forceinline__ float ciou_masked(float4 a, float4 b, float m,
                                             float bn, float* acc) {
    float iw = fminf(a.z, b.z) - fmaxf(a.x, b.x); iw = fmaxf(iw, 0.0f);
    float ih = fminf(a.w, b.w) - fmaxf(a.y, b.y); ih = fmaxf(ih, 0.0f);
    float inter = iw * ih;

    float wa = a.z - a.x, ha = a.w - a.y;
    float wb = b.z - b.x, hb = b.w - b.y;
    float uni = wa * ha + wb * hb - inter;
    float iou = inter * __builtin_amdgcn_rcpf(uni + EPSF);

    float cw = fmaxf(a.z, b.z) - fminf(a.x, b.x);
    float ch = fmaxf(a.w, b.w) - fminf(a.y, b.y);
    float c2 = fmaf(cw, cw, fmaf(ch, ch, EPSF));

    float dx = (b.x + b.z - a.x - a.z) * 0.5f;
    float dy = (b.y + b.w - a.y - a.w) * 0.5f;
    float rho2 = fmaf(dx, dx, dy * dy);

    // atan(wb/hb') - atan(wa/ha') = atan((wb*ha' - wa*hb')/(ha'*hb' + wa*wb))
    float hap = ha + EPSF, hbp = hb + EPSF;
    float num = fmaf(wb, hap, -wa * hbp);
    float den = fmaf(hap, hbp, wa * wb);
    float datan = fast_atan(num * __builtin_amdgcn_rcpf(den));

    const float c4pi2 = 0.40528473456f;      // 4/pi^2
    float v = c4pi2 * datan * datan;
    float av = v * v * __builtin_amdgcn_rcpf(1.0f - iou + v + EPSF); // alpha*v

    float ciou = iou - rho2 * __builtin_amdgcn_rcpf(c2) - av;
    float iou_m = ciou * m;
    *acc += (1.0f - iou_m) * bn * m;
    return iou_m;
}

// Main kernel. __launch_bounds__(256, 4): 4 waves/EU min -> ~128-VGPR budget,
// so the 16-load batch (≈40 dest VGPRs) can actually stay in flight.
// (R2's VGPR_Count=36 proved the default budget serialized the loads.)
__global__ __launch_bounds__(256, 4) void box_loss_main(
    const float4* __restrict__ pb, const float4* __restrict__ tb,
    const int*    __restrict__ mask, const float* __restrict__ bnorm,
    float* __restrict__ iou_out, float* __restrict__ partials, int n)
{
    const int stride = gridDim.x * blockDim.x;
    const int tid = blockIdx.x * blockDim.x + threadIdx.x;
    float acc = 0.0f;

    float4 a[UNROLL], b[UNROLL];
    int    mk[UNROLL];
    float  bn[UNROLL];
    int    idx[UNROLL];
    #pragma unroll
    for (int u = 0; u < UNROLL; ++u) {
        int i = tid + u * stride;
        idx[u] = i;
        if (i < n) { a[u] = pb[i]; b[u] = tb[i]; mk[u] = mask[i]; bn[u] = bnorm[i]; }
        else       { mk[u] = 0; bn[u] = 0.0f;
                     a[u] = make_float4(0,0,1,1); b[u] = make_float4(0,0,1,1); }
    }
    #pragma unroll
    for (int u = 0; u < UNROLL; ++u) {
        float r = ciou_masked(a[u], b[u], (float)mk[u], bn[u], &acc);
        if (idx[u] < n) iou_out[idx[u]] = r;
    }

    // wave64 reduction
    #pragma unroll
    for (int off = 32; off > 0; off >>= 1)
        acc += __shfl_down(acc, off, 64);

    __shared__ float lds[4];
    const int lane = threadIdx.x & 63;
    const int wid  = threadIdx.x >> 6;
    if (lane == 0) lds[wid] = acc;
    __syncthreads();
    if (threadIdx.x == 0)
        partials[blockIdx.x] = lds[0] + lds[1] + lds[2] + lds[3];
}

// Finisher: one block reduces the per-block partials, writes out[0].
__global__ __launch_bounds__(256) void box_loss_final(
    const float* __restrict__ partials, const float* __restrict__ cls_norm,
    float* __restrict__ out, int nblocks)
{
    float acc = 0.0f;
    for (int i = threadIdx.x; i < nblocks; i += 256) acc += partials[i];

    #pragma unroll
    for (int off = 32; off > 0; off >>= 1)
        acc += __shfl_down(acc, off, 64);

    __shared__ float lds[4];
    const int lane = threadIdx.x & 63;
    const int wid  = threadIdx.x >> 6;
    if (lane == 0) lds[wid] = acc;
    __syncthreads();
    if (threadIdx.x == 0)
        out[0] = (lds[0] + lds[1] + lds[2] + lds[3]) / cls_norm[0];
}

extern "C" void kernel_launch(void* const* d_in, const int* in_sizes, int n_in,
                              void* d_out, int out_size, void* d_ws, size_t ws_size,
                              hipStream_t stream) {
    const float4* pb    = (const float4*)d_in[0];
    const float4* tb    = (const float4*)d_in[1];
    const int*    mask  = (const int*)  d_in[2];
    const float*  bnorm = (const float*)d_in[3];
    const float*  cls   = (const float*)d_in[4];
    float*        out   = (float*)d_out;
    float*        part  = (float*)d_ws;           // per-block partials
    const int n = in_sizes[2];                    // B*A = 2,150,400

    const int block = 256;
    const int per_block = block * UNROLL;         // 1024 elems/block
    const int grid = (n + per_block - 1) / per_block;  // 2100

    box_loss_main<<<grid, block, 0, stream>>>(pb, tb, mask, bnorm,
                                              out + 1, part, n);
    box_loss_final<<<1, block, 0, stream>>>(part, cls, out, grid);
}

// Round 5
// 116.805 us; speedup vs baseline: 1.1477x; 1.0114x over previous
//
#include <hip/hip_runtime.h>
#include <math.h>

#define EPSF 1e-9f
#define DEPTH 8   // elems per thread: 64 lanes x 40 B x 8 = 5 KB in flight/wave

// Cheap atan: degree-9 odd minimax poly on [0,1], range-reduce via
// atan(z) = pi/2 - atan(1/z) for |z|>1. Max abs err ~1e-5 (threshold 2.6e-2).
__device__ __forceinline__ float fast_atan(float z) {
    float az = fabsf(z);
    float rz = __builtin_amdgcn_rcpf(az);
    float t  = az > 1.0f ? rz : az;          // t in [0,1]
    float t2 = t * t;
    float p = fmaf(t2, 0.0208351f, -0.0851330f);
    p = fmaf(t2, p, 0.1801410f);
    p = fmaf(t2, p, -0.3302995f);
    p = fmaf(t2, p, 0.9998660f);
    p = p * t;
    float r = az > 1.0f ? 1.5707963f - p : p;
    return z < 0.0f ? -r : r;
}

__device__ __forceinline__ float ciou_masked(float4 a, float4 b, float m,
                                             float bn, float* acc) {
    float iw = fminf(a.z, b.z) - fmaxf(a.x, b.x); iw = fmaxf(iw, 0.0f);
    float ih = fminf(a.w, b.w) - fmaxf(a.y, b.y); ih = fmaxf(ih, 0.0f);
    float inter = iw * ih;

    float wa = a.z - a.x, ha = a.w - a.y;
    float wb = b.z - b.x, hb = b.w - b.y;
    float uni = wa * ha + wb * hb - inter;
    float iou = inter * __builtin_amdgcn_rcpf(uni + EPSF);

    float cw = fmaxf(a.z, b.z) - fminf(a.x, b.x);
    float ch = fmaxf(a.w, b.w) - fminf(a.y, b.y);
    float c2 = fmaf(cw, cw, fmaf(ch, ch, EPSF));

    float dx = (b.x + b.z - a.x - a.z) * 0.5f;
    float dy = (b.y + b.w - a.y - a.w) * 0.5f;
    float rho2 = fmaf(dx, dx, dy * dy);

    // atan(wb/hb') - atan(wa/ha') = atan((wb*ha' - wa*hb')/(ha'*hb' + wa*wb))
    float hap = ha + EPSF, hbp = hb + EPSF;
    float num = fmaf(wb, hap, -wa * hbp);
    float den = fmaf(hap, hbp, wa * wb);
    float datan = fast_atan(num * __builtin_amdgcn_rcpf(den));

    const float c4pi2 = 0.40528473456f;      // 4/pi^2
    float v = c4pi2 * datan * datan;
    float av = v * v * __builtin_amdgcn_rcpf(1.0f - iou + v + EPSF); // alpha*v

    float ciou = iou - rho2 * __builtin_amdgcn_rcpf(c2) - av;
    float iou_m = ciou * m;
    *acc += (1.0f - iou_m) * bn * m;
    return iou_m;
}

__device__ __forceinline__ void block_reduce_store(float acc, float* dst) {
    #pragma unroll
    for (int off = 32; off > 0; off >>= 1)
        acc += __shfl_down(acc, off, 64);
    __shared__ float lds[4];
    const int lane = threadIdx.x & 63;
    const int wid  = threadIdx.x >> 6;
    if (lane == 0) lds[wid] = acc;
    __syncthreads();
    if (threadIdx.x == 0) *dst = lds[0] + lds[1] + lds[2] + lds[3];
}

// Guard-free deep-batch kernel: block covers exactly 2048 consecutive elems;
// all 32 vmem loads issued before any compute (bytes-in-flight ~40 KB/CU).
__global__ __launch_bounds__(256, 4) void box_loss_deep(
    const float4* __restrict__ pb, const float4* __restrict__ tb,
    const int*    __restrict__ mask, const float* __restrict__ bnorm,
    float* __restrict__ iou_out, float* __restrict__ partials)
{
    const int base = blockIdx.x * (256 * DEPTH) + threadIdx.x;
    float acc = 0.0f;

    float4 a[DEPTH], b[DEPTH];
    int    mk[DEPTH];
    float  bn[DEPTH];
    #pragma unroll
    for (int u = 0; u < DEPTH; ++u) {
        int i = base + u * 256;
        a[u] = pb[i]; b[u] = tb[i]; mk[u] = mask[i]; bn[u] = bnorm[i];
    }
    #pragma unroll
    for (int u = 0; u < DEPTH; ++u) {
        int i = base + u * 256;
        iou_out[i] = ciou_masked(a[u], b[u], (float)mk[u], bn[u], &acc);
    }
    block_reduce_store(acc, &partials[blockIdx.x]);
}

// Guarded tail (only launched if n % 2048 != 0; for this problem rem == 0).
__global__ __launch_bounds__(256) void box_loss_tail(
    const float4* __restrict__ pb, const float4* __restrict__ tb,
    const int*    __restrict__ mask, const float* __restrict__ bnorm,
    float* __restrict__ iou_out, float* __restrict__ partials,
    int start, int n)
{
    const int i = start + blockIdx.x * blockDim.x + threadIdx.x;
    float acc = 0.0f;
    float r = 0.0f;
    bool ok = i < n;
    if (ok) r = ciou_masked(pb[i], tb[i], (float)mask[i], bnorm[i], &acc);
    if (ok) iou_out[i] = r;
    block_reduce_store(acc, &partials[blockIdx.x]);
}

// Finisher: one block reduces per-block partials, writes out[0].
__global__ __launch_bounds__(256) void box_loss_final(
    const float* __restrict__ partials, const float* __restrict__ cls_norm,
    float* __restrict__ out, int nparts)
{
    float acc = 0.0f;
    for (int i = threadIdx.x; i < nparts; i += 256) acc += partials[i];
    #pragma unroll
    for (int off = 32; off > 0; off >>= 1)
        acc += __shfl_down(acc, off, 64);
    __shared__ float lds[4];
    const int lane = threadIdx.x & 63;
    const int wid  = threadIdx.x >> 6;
    if (lane == 0) lds[wid] = acc;
    __syncthreads();
    if (threadIdx.x == 0)
        out[0] = (lds[0] + lds[1] + lds[2] + lds[3]) / cls_norm[0];
}

extern "C" void kernel_launch(void* const* d_in, const int* in_sizes, int n_in,
                              void* d_out, int out_size, void* d_ws, size_t ws_size,
                              hipStream_t stream) {
    const float4* pb    = (const float4*)d_in[0];
    const float4* tb    = (const float4*)d_in[1];
    const int*    mask  = (const int*)  d_in[2];
    const float*  bnorm = (const float*)d_in[3];
    const float*  cls   = (const float*)d_in[4];
    float*        out   = (float*)d_out;
    float*        part  = (float*)d_ws;
    const int n = in_sizes[2];                    // B*A = 2,150,400

    const int per_block = 256 * DEPTH;            // 2048
    const int full = n / per_block;               // 1050 (exact for this n)
    const int rem  = n - full * per_block;

    if (full > 0)
        box_loss_deep<<<full, 256, 0, stream>>>(pb, tb, mask, bnorm,
                                                out + 1, part);
    int nparts = full;
    if (rem > 0) {
        const int tg = (rem + 255) / 256;
        box_loss_tail<<<tg, 256, 0, stream>>>(pb, tb, mask, bnorm, out + 1,
                                              part + full, full * per_block, n);
        nparts += tg;
    }
    box_loss_final<<<1, 256, 0, stream>>>(part, cls, out, nparts);
}